// Round 2
// baseline (1115.120 us; speedup 1.0000x reference)
//
#include <hip/hip_runtime.h>
#include <stdint.h>

// ---------------------------------------------------------------------------
// GNN MetaLayer on MI355X (gfx950). Dtype-self-detecting:
//   flags[0] = 1 if float tensors are f32 (else bf16), detected from x bits
//   flags[1] = 1 if edge_index is int64 (else int32), detected from odd words
// Compute: bf16 MFMA 16x16x32, f32 accumulate, f32 atomic scatter-mean.
//   edge_out = relu([x[row]|x[col]|ea] @ We1 + be1) @ We2 + be2        [E,128]
//   mean     = scatter_mean(edge_out, row)                              [N,128]
//   x_out    = relu([x|mean] @ Wn1 + bn1) @ Wn2 + bn2                   [N,128]
// d_out = [x_out | edge_out] in the detected float dtype.
//
// Workspace layout (bytes):
//   0         flags    2 ints
//   256       biasf    512 f32  [be1|be2|bn1|bn2]                2048
//   4096      WT1      [128][384] bf16 (We1^T)                  98304
//   102400    WT2      [128][128] bf16                          32768
//   135168    WnT1     [128][256] bf16                          65536
//   200704    WnT2     [128][128] bf16                          32768
//   233472    eidx32   [2][640000] int32                      5120000
//   5353472   agg      [50000][128] f32 (atomic target)      25600000
//   30953472  cnt      [50000] f32                              200000
//   31153472  meanb    [50000][128] bf16                     12800000
//   43953472  xb       [50000][128] bf16                     12800000
//   total ~54.2 MB
// ---------------------------------------------------------------------------

#define E_EDGES 640000
#define N_NODES 50000
#define DIM 128

typedef unsigned short u16;
typedef unsigned int u32x4 __attribute__((ext_vector_type(4)));
typedef float f32x4 __attribute__((ext_vector_type(4)));
typedef short s16x8 __attribute__((ext_vector_type(8)));
union U16 { u32x4 u; s16x8 s; u16 h[8]; };

__device__ __forceinline__ float b2f(u16 u) {
  union { unsigned i; float f; } v; v.i = ((unsigned)u) << 16; return v.f;
}
__device__ __forceinline__ u16 f2b(float f) {
  union { float f; unsigned u; } v; v.f = f;
  unsigned r = v.u + 0x7FFFu + ((v.u >> 16) & 1u);
  return (u16)(r >> 16);
}
__device__ __forceinline__ float ldf(const void* p, long long i, int isF32) {
  return isF32 ? ((const float*)p)[i] : b2f(((const u16*)p)[i]);
}

// ----------------------------- dtype detector ------------------------------
__global__ void detect_kernel(const void* x, const void* ei, int* flags) {
  __shared__ int sBig, sNz;
  if (threadIdx.x == 0) { sBig = 0; sNz = 0; }
  __syncthreads();
  const u16* xu = (const u16*)x;
  const int* ew = (const int*)ei;
  int big = 0, nz = 0;
  for (int i = threadIdx.x; i < 4096; i += 256) {
    u16 u = xu[2 * i];                       // even half-words
    if (((u >> 7) & 0xFF) >= 0x90) big = 1;  // impossible for bf16 N(0,1)
    if (ew[2 * i + 1] != 0) nz = 1;          // odd words all 0 <=> int64
  }
  if (big) atomicOr(&sBig, 1);
  if (nz) atomicOr(&sNz, 1);
  __syncthreads();
  if (threadIdx.x == 0) { flags[0] = sBig; flags[1] = sNz ? 0 : 1; }
}

// --------------------------- index normalization ---------------------------
__global__ void normalize_idx(const void* ei, const int* __restrict__ flags,
                              int* __restrict__ out) {
  int i = blockIdx.x * 256 + threadIdx.x;   // grid covers 2*E exactly
  if (flags[1]) out[i] = (int)((const long long*)ei)[i];
  else          out[i] = ((const int*)ei)[i];
}

// --------------------------- weight prep (bf16^T) --------------------------
__global__ void prep_weights(const void* We1, const void* be1, const void* We2,
                             const void* be2, const void* Wn1, const void* bn1,
                             const void* Wn2, const void* bn2,
                             const int* __restrict__ flags,
                             u16* __restrict__ WT1, u16* __restrict__ WT2,
                             u16* __restrict__ WnT1, u16* __restrict__ WnT2,
                             float* __restrict__ biasf) {
  const int isF32 = flags[0];
  int tid = blockIdx.x * 256 + threadIdx.x;
  if (tid < 384 * 128) { int k = tid >> 7, n = tid & 127; WT1 [n * 384 + k] = f2b(ldf(We1, tid, isF32)); }
  if (tid < 128 * 128) { int k = tid >> 7, n = tid & 127; WT2 [n * 128 + k] = f2b(ldf(We2, tid, isF32)); }
  if (tid < 256 * 128) { int k = tid >> 7, n = tid & 127; WnT1[n * 256 + k] = f2b(ldf(Wn1, tid, isF32)); }
  if (tid < 128 * 128) { int k = tid >> 7, n = tid & 127; WnT2[n * 128 + k] = f2b(ldf(Wn2, tid, isF32)); }
  if (tid < 128) {
    biasf[tid]       = ldf(be1, tid, isF32);
    biasf[128 + tid] = ldf(be2, tid, isF32);
    biasf[256 + tid] = ldf(bn1, tid, isF32);
    biasf[384 + tid] = ldf(bn2, tid, isF32);
  }
}

// ------------------------------ x -> bf16 ----------------------------------
__global__ void convert_x(const void* x, const int* __restrict__ flags,
                          u16* __restrict__ xb) {
  int i = blockIdx.x * 256 + threadIdx.x;   // grid covers N*DIM exactly
  xb[i] = flags[0] ? f2b(((const float*)x)[i]) : ((const u16*)x)[i];
}

// ------------------------------ edge kernel --------------------------------
// block = 256 thr (4 waves), wave = 32 edges (2 M-tiles of 16), grid = E/128.
// MFMA 16x16x32 bf16: A[m=lane&15][k=quad*8+j], B[n=lane&15][k=quad*8+j],
//                     D[row=quad*4+r][col=lane&15].
__global__ __launch_bounds__(256) void edge_kernel(
    const u16* __restrict__ xb, const int* __restrict__ ei, const void* ea,
    const u16* __restrict__ WT1, const u16* __restrict__ WT2,
    const float* __restrict__ biasf, const int* __restrict__ flags,
    void* d_out, float* __restrict__ agg, float* __restrict__ cnt) {
  __shared__ u16 h[4][32 * 136];   // per-wave 32x128 hidden tile, stride 136
  const int isF32 = flags[0];
  const int wid = threadIdx.x >> 6, lane = threadIdx.x & 63;
  const int lm = lane & 15, quad = lane >> 4;
  const int ebase = (blockIdx.x * 4 + wid) * 32;

  if (threadIdx.x < 128)
    atomicAdd(&cnt[ei[blockIdx.x * 128 + threadIdx.x]], 1.0f);

  const int e0 = ebase + lm, e1 = ebase + 16 + lm;
  const int row0 = ei[e0], col0 = ei[E_EDGES + e0];
  const int row1 = ei[e1], col1 = ei[E_EDGES + e1];

  const f32x4 fz = {0.f, 0.f, 0.f, 0.f};
  f32x4 acc[2][8];
#pragma unroll
  for (int mt = 0; mt < 2; ++mt)
#pragma unroll
    for (int t = 0; t < 8; ++t) acc[mt][t] = fz;

  // ---- layer 1: [32,384] @ [384,128] ----
#pragma unroll
  for (int ks = 0; ks < 12; ++ks) {
    const int k0 = ks * 32 + quad * 8;
    U16 a0, a1;
    if (k0 < 256) {
      const u16 *p0, *p1;
      if (k0 < 128) { p0 = xb + (size_t)row0 * DIM + k0;         p1 = xb + (size_t)row1 * DIM + k0; }
      else          { p0 = xb + (size_t)col0 * DIM + (k0 - 128); p1 = xb + (size_t)col1 * DIM + (k0 - 128); }
      a0.u = *(const u32x4*)p0;
      a1.u = *(const u32x4*)p1;
    } else {
      const int off = k0 - 256;
      if (isF32) {
        const float* q0 = (const float*)ea + (size_t)e0 * DIM + off;
        const float* q1 = (const float*)ea + (size_t)e1 * DIM + off;
        f32x4 lo0 = *(const f32x4*)q0, hi0 = *(const f32x4*)(q0 + 4);
        f32x4 lo1 = *(const f32x4*)q1, hi1 = *(const f32x4*)(q1 + 4);
#pragma unroll
        for (int j = 0; j < 4; ++j) {
          a0.h[j] = f2b(lo0[j]); a0.h[4 + j] = f2b(hi0[j]);
          a1.h[j] = f2b(lo1[j]); a1.h[4 + j] = f2b(hi1[j]);
        }
      } else {
        const u16* q0 = (const u16*)ea + (size_t)e0 * DIM + off;
        const u16* q1 = (const u16*)ea + (size_t)e1 * DIM + off;
        a0.u = *(const u32x4*)q0;
        a1.u = *(const u32x4*)q1;
      }
    }
#pragma unroll
    for (int t = 0; t < 8; ++t) {
      U16 b; b.u = *(const u32x4*)(WT1 + (t * 16 + lm) * 384 + k0);
      acc[0][t] = __builtin_amdgcn_mfma_f32_16x16x32_bf16(a0.s, b.s, acc[0][t], 0, 0, 0);
      acc[1][t] = __builtin_amdgcn_mfma_f32_16x16x32_bf16(a1.s, b.s, acc[1][t], 0, 0, 0);
    }
  }

  // bias + relu -> LDS (bf16)
  u16* hw = h[wid];
#pragma unroll
  for (int t = 0; t < 8; ++t) {
    const int n = t * 16 + lm;
    const float bias = biasf[n];           // be1
#pragma unroll
    for (int mt = 0; mt < 2; ++mt)
#pragma unroll
      for (int r = 0; r < 4; ++r) {
        float v = acc[mt][t][r] + bias;
        v = v > 0.f ? v : 0.f;
        hw[(mt * 16 + quad * 4 + r) * 136 + n] = f2b(v);
      }
  }
  __syncthreads();

  // ---- layer 2: [32,128] @ [128,128] ----
  f32x4 acc2[2][8];
#pragma unroll
  for (int mt = 0; mt < 2; ++mt)
#pragma unroll
    for (int t = 0; t < 8; ++t) acc2[mt][t] = fz;

#pragma unroll
  for (int ks = 0; ks < 4; ++ks) {
    const int k0 = ks * 32 + quad * 8;
    U16 a0, a1;
    a0.u = *(const u32x4*)(hw + lm * 136 + k0);
    a1.u = *(const u32x4*)(hw + (16 + lm) * 136 + k0);
#pragma unroll
    for (int t = 0; t < 8; ++t) {
      U16 b; b.u = *(const u32x4*)(WT2 + (t * 16 + lm) * 128 + k0);
      acc2[0][t] = __builtin_amdgcn_mfma_f32_16x16x32_bf16(a0.s, b.s, acc2[0][t], 0, 0, 0);
      acc2[1][t] = __builtin_amdgcn_mfma_f32_16x16x32_bf16(a1.s, b.s, acc2[1][t], 0, 0, 0);
    }
  }

  // epilogue: bias, scatter atomicAdd, store edge_out in detected dtype
  int rowd[2][4];
#pragma unroll
  for (int mt = 0; mt < 2; ++mt)
#pragma unroll
    for (int r = 0; r < 4; ++r)
      rowd[mt][r] = ei[ebase + mt * 16 + quad * 4 + r];

  float* eoutf = (float*)d_out + (size_t)N_NODES * DIM;
  u16*   eoutb = (u16*)d_out   + (size_t)N_NODES * DIM;

#pragma unroll
  for (int t = 0; t < 8; ++t) {
    const int n = t * 16 + lm;
    const float bias = biasf[128 + n];     // be2
#pragma unroll
    for (int mt = 0; mt < 2; ++mt)
#pragma unroll
      for (int r = 0; r < 4; ++r) {
        float v = acc2[mt][t][r] + bias;
        const size_t e = (size_t)(ebase + mt * 16 + quad * 4 + r);
        atomicAdd(&agg[(size_t)rowd[mt][r] * DIM + n], v);
        if (isF32) eoutf[e * DIM + n] = v;
        else       eoutb[e * DIM + n] = f2b(v);
      }
  }
}

// ------------------------------ mean kernel --------------------------------
__global__ void mean_kernel(const float* __restrict__ agg,
                            const float* __restrict__ cnt,
                            u16* __restrict__ meanb) {
  int tid = blockIdx.x * 256 + threadIdx.x;   // grid covers N*DIM exactly
  float c = cnt[tid >> 7];
  meanb[tid] = f2b(agg[tid] / fmaxf(c, 1.0f));
}

// ------------------------------ node kernel --------------------------------
__global__ __launch_bounds__(256) void node_kernel(
    const u16* __restrict__ xb, const u16* __restrict__ meanb,
    const u16* __restrict__ WnT1, const u16* __restrict__ WnT2,
    const float* __restrict__ biasf, const int* __restrict__ flags,
    void* d_out) {
  __shared__ u16 h[4][32 * 136];
  const int isF32 = flags[0];
  const int wid = threadIdx.x >> 6, lane = threadIdx.x & 63;
  const int lm = lane & 15, quad = lane >> 4;
  const int nbase = (blockIdx.x * 4 + wid) * 32;

  int nd0 = nbase + lm;      if (nd0 > N_NODES - 1) nd0 = N_NODES - 1;
  int nd1 = nbase + 16 + lm; if (nd1 > N_NODES - 1) nd1 = N_NODES - 1;

  const f32x4 fz = {0.f, 0.f, 0.f, 0.f};
  f32x4 acc[2][8];
#pragma unroll
  for (int mt = 0; mt < 2; ++mt)
#pragma unroll
    for (int t = 0; t < 8; ++t) acc[mt][t] = fz;

  // ---- layer 1: [32,256] @ [256,128] ----
#pragma unroll
  for (int ks = 0; ks < 8; ++ks) {
    const int k0 = ks * 32 + quad * 8;
    const u16 *p0, *p1;
    if (k0 < 128) { p0 = xb + (size_t)nd0 * DIM + k0;            p1 = xb + (size_t)nd1 * DIM + k0; }
    else          { p0 = meanb + (size_t)nd0 * DIM + (k0 - 128); p1 = meanb + (size_t)nd1 * DIM + (k0 - 128); }
    U16 a0, a1;
    a0.u = *(const u32x4*)p0;
    a1.u = *(const u32x4*)p1;
#pragma unroll
    for (int t = 0; t < 8; ++t) {
      U16 b; b.u = *(const u32x4*)(WnT1 + (t * 16 + lm) * 256 + k0);
      acc[0][t] = __builtin_amdgcn_mfma_f32_16x16x32_bf16(a0.s, b.s, acc[0][t], 0, 0, 0);
      acc[1][t] = __builtin_amdgcn_mfma_f32_16x16x32_bf16(a1.s, b.s, acc[1][t], 0, 0, 0);
    }
  }

  u16* hw = h[wid];
#pragma unroll
  for (int t = 0; t < 8; ++t) {
    const int n = t * 16 + lm;
    const float bias = biasf[256 + n];     // bn1
#pragma unroll
    for (int mt = 0; mt < 2; ++mt)
#pragma unroll
      for (int r = 0; r < 4; ++r) {
        float v = acc[mt][t][r] + bias;
        v = v > 0.f ? v : 0.f;
        hw[(mt * 16 + quad * 4 + r) * 136 + n] = f2b(v);
      }
  }
  __syncthreads();

  // ---- layer 2: [32,128] @ [128,128] ----
  f32x4 acc2[2][8];
#pragma unroll
  for (int mt = 0; mt < 2; ++mt)
#pragma unroll
    for (int t = 0; t < 8; ++t) acc2[mt][t] = fz;

#pragma unroll
  for (int ks = 0; ks < 4; ++ks) {
    const int k0 = ks * 32 + quad * 8;
    U16 a0, a1;
    a0.u = *(const u32x4*)(hw + lm * 136 + k0);
    a1.u = *(const u32x4*)(hw + (16 + lm) * 136 + k0);
#pragma unroll
    for (int t = 0; t < 8; ++t) {
      U16 b; b.u = *(const u32x4*)(WnT2 + (t * 16 + lm) * 128 + k0);
      acc2[0][t] = __builtin_amdgcn_mfma_f32_16x16x32_bf16(a0.s, b.s, acc2[0][t], 0, 0, 0);
      acc2[1][t] = __builtin_amdgcn_mfma_f32_16x16x32_bf16(a1.s, b.s, acc2[1][t], 0, 0, 0);
    }
  }

  float* xoutf = (float*)d_out;
  u16*   xoutb = (u16*)d_out;
#pragma unroll
  for (int t = 0; t < 8; ++t) {
    const int n = t * 16 + lm;
    const float bias = biasf[384 + n];     // bn2
#pragma unroll
    for (int mt = 0; mt < 2; ++mt)
#pragma unroll
      for (int r = 0; r < 4; ++r) {
        const int node = nbase + mt * 16 + quad * 4 + r;
        if (node < N_NODES) {
          float v = acc2[mt][t][r] + bias;
          if (isF32) xoutf[(size_t)node * DIM + n] = v;
          else       xoutb[(size_t)node * DIM + n] = f2b(v);
        }
      }
  }
}

// ------------------------------- launcher ----------------------------------
extern "C" void kernel_launch(void* const* d_in, const int* in_sizes, int n_in,
                              void* d_out, int out_size, void* d_ws, size_t ws_size,
                              hipStream_t stream) {
  const void* x   = d_in[0];
  const void* ei  = d_in[1];
  const void* ea  = d_in[2];
  const void* We1 = d_in[3]; const void* be1 = d_in[4];
  const void* We2 = d_in[5]; const void* be2 = d_in[6];
  const void* Wn1 = d_in[7]; const void* bn1 = d_in[8];
  const void* Wn2 = d_in[9]; const void* bn2 = d_in[10];

  char* ws = (char*)d_ws;
  int*   flags  = (int*)(ws + 0);
  float* biasf  = (float*)(ws + 256);
  u16*   WT1    = (u16*)(ws + 4096);
  u16*   WT2    = (u16*)(ws + 102400);
  u16*   WnT1   = (u16*)(ws + 135168);
  u16*   WnT2   = (u16*)(ws + 200704);
  int*   eidx32 = (int*)(ws + 233472);
  float* agg    = (float*)(ws + 5353472);
  float* cnt    = (float*)(ws + 30953472);
  u16*   meanb  = (u16*)(ws + 31153472);
  u16*   xb     = (u16*)(ws + 43953472);

  hipMemsetAsync(ws + 5353472, 0, 25800000, stream);  // agg + cnt

  detect_kernel<<<1, 256, 0, stream>>>(x, ei, flags);
  normalize_idx<<<2 * E_EDGES / 256, 256, 0, stream>>>(ei, flags, eidx32);
  prep_weights<<<192, 256, 0, stream>>>(We1, be1, We2, be2, Wn1, bn1, Wn2, bn2,
                                        flags, WT1, WT2, WnT1, WnT2, biasf);
  convert_x<<<N_NODES * DIM / 256, 256, 0, stream>>>(x, flags, xb);
  edge_kernel<<<E_EDGES / 128, 256, 0, stream>>>(xb, eidx32, ea, WT1, WT2,
                                                 biasf, flags, d_out, agg, cnt);
  mean_kernel<<<N_NODES * DIM / 256, 256, 0, stream>>>(agg, cnt, meanb);
  node_kernel<<<(N_NODES + 127) / 128, 256, 0, stream>>>(xb, meanb, WnT1, WnT2,
                                                         biasf, flags, d_out);
}